// Round 1
// baseline (5114.400 us; speedup 1.0000x reference)
//
#include <hip/hip_runtime.h>
#include <stdint.h>

#define T_STEPS 64
#define B_SZ    64
#define H_SZ    512
#define E_SZ    256
#define V_SZ    32000
#define G4      2048   // 4*H

typedef _Float16 f16;
typedef _Float16 f16x2 __attribute__((ext_vector_type(2)));
typedef _Float16 f16x4 __attribute__((ext_vector_type(4)));
typedef _Float16 f16x8 __attribute__((ext_vector_type(8)));
typedef float    f32x4 __attribute__((ext_vector_type(4)));

// ---- addrspace helpers for global_load_lds (generic->AS via integer, compile-safe) ----
#define GLL(g, l) __builtin_amdgcn_global_load_lds(                                   \
    (const __attribute__((address_space(1))) void*)(uintptr_t)(g),                    \
    (__attribute__((address_space(3))) void*)(uint32_t)(uintptr_t)(l), 16, 0, 0)

#if __has_builtin(__builtin_amdgcn_fdot2)
#define FDOT2(a, b, c) __builtin_amdgcn_fdot2((a), (b), (c), false)
#else
#define FDOT2(a, b, c) ((float)(a)[0]*(float)(b)[0] + (float)(a)[1]*(float)(b)[1] + (c))
#endif

__device__ __forceinline__ float sigmoidf_fast(float x) {
    return 1.0f / (1.0f + __expf(-x));          // safe for all x (exp>=0)
}
__device__ __forceinline__ float tanhf_fast(float x) {
    return 2.0f / (1.0f + __expf(-2.0f * x)) - 1.0f;  // safe for all x
}

__device__ __forceinline__ f16x4 cvt4(float4 s) {
    f16x4 d; d[0] = (f16)s.x; d[1] = (f16)s.y; d[2] = (f16)s.z; d[3] = (f16)s.w; return d;
}

__device__ __forceinline__ float dot8(f16x8 w, f16x8 h, float acc) {
    f16x2 w0 = {w[0], w[1]}, w1 = {w[2], w[3]}, w2 = {w[4], w[5]}, w3 = {w[6], w[7]};
    f16x2 h0 = {h[0], h[1]}, h1 = {h[2], h[3]}, h2 = {h[4], h[5]}, h3 = {h[6], h[7]};
    acc = FDOT2(w0, h0, acc);
    acc = FDOT2(w1, h1, acc);
    acc = FDOT2(w2, h2, acc);
    acc = FDOT2(w3, h3, acc);
    return acc;
}

// ---------------------------------------------------------------------------
// Prep: convert W_out/W_ih to f16, reorder W_hh -> Wr[j][gate][k] f16,
// gather+convert embeddings X[tb][e] f16 (tokens = [SOS, y[:-1]]), bsum=b_ih+b_hh
// ---------------------------------------------------------------------------
__global__ __launch_bounds__(256) void prep_kernel(
    const float* __restrict__ Wih, const float* __restrict__ Whh,
    const float* __restrict__ Wout, const float* __restrict__ bih,
    const float* __restrict__ bhh, const float* __restrict__ embed,
    const int* __restrict__ y,
    f16* __restrict__ Xf, f16* __restrict__ Wihf, f16* __restrict__ Wrf,
    f16* __restrict__ Woutf, float* __restrict__ bsum)
{
    const int NW_OUT = V_SZ * H_SZ / 4;          // 4,096,000
    const int NW_IH  = G4 * E_SZ / 4;            // 131,072
    const int NW_HH  = G4 * H_SZ / 4;            // 262,144
    const int NW_X   = T_STEPS * B_SZ * E_SZ / 4;// 262,144
    const int NW_B   = G4 / 4;                   // 512
    const int total  = NW_OUT + NW_IH + NW_HH + NW_X + NW_B;

    for (int u = blockIdx.x * blockDim.x + threadIdx.x; u < total;
         u += gridDim.x * blockDim.x) {
        int v = u;
        if (v < NW_OUT) {                          // W_out straight convert
            ((f16x4*)Woutf)[v] = cvt4(((const float4*)Wout)[v]);
            continue;
        }
        v -= NW_OUT;
        if (v < NW_IH) {                           // W_ih straight convert
            ((f16x4*)Wihf)[v] = cvt4(((const float4*)Wih)[v]);
            continue;
        }
        v -= NW_IH;
        if (v < NW_HH) {                           // W_hh reorder: Wr[(j*4+g)*512+k]=Whh[g*512+j][k]
            int row = v >> 7;                      // /(512/4)
            int k4  = v & 127;
            int j = row >> 2, g = row & 3;
            ((f16x4*)Wrf)[v] = cvt4(((const float4*)Whh)[(g * H_SZ + j) * (H_SZ / 4) + k4]);
            continue;
        }
        v -= NW_HH;
        if (v < NW_X) {                            // embed gather
            int tb = v >> 6;                       // /(256/4)
            int e4 = v & 63;
            int t = tb >> 6, b = tb & 63;
            int tok = (t == 0) ? 1 : y[(t - 1) * B_SZ + b];
            ((f16x4*)Xf)[v] = cvt4(((const float4*)embed)[tok * (E_SZ / 4) + e4]);
            continue;
        }
        v -= NW_X;                                 // bias sum
        float4 a = ((const float4*)bih)[v];
        float4 b = ((const float4*)bhh)[v];
        float4 s; s.x = a.x + b.x; s.y = a.y + b.y; s.z = a.z + b.z; s.w = a.w + b.w;
        ((float4*)bsum)[v] = s;
    }
}

// ---------------------------------------------------------------------------
// MFMA f16 GEMM: C[M,N] = A[M,K] @ B[N,K]^T + bias[N]   (f32 out)
// 128x128 tile, 4 waves (2x2), each wave 64x64 = 4x4 of 16x16x32 MFMA.
// global_load_lds width-16 staging. M%128==0, N%128==0, K%32==0 required.
// ---------------------------------------------------------------------------
template <int K>
__global__ __launch_bounds__(256) void gemm_f16(
    const f16* __restrict__ A, const f16* __restrict__ Bm,
    const float* __restrict__ bias, float* __restrict__ C, int N)
{
    __shared__ f16 As[128 * 32];
    __shared__ f16 Bs[128 * 32];
    const int tid  = threadIdx.x;
    const int wave = tid >> 6;
    const int lane = tid & 63;
    const int m0 = blockIdx.y * 128;
    const int n0 = blockIdx.x * 128;
    const int wm = (wave >> 1) * 64;
    const int wn = (wave & 1) * 64;

    f32x4 acc[4][4] = {};

    // staging: wave covers rows [wave*32, wave*32+32) via 2 instrs (16 rows each);
    // lane -> row = lane>>2, 16B chunk = lane&3 (row = 32 f16 = 64B = 4 chunks)
    const int srow = wave * 32 + (lane >> 2);
    const int skk  = (lane & 3) * 8;
    const f16* gA0 = A + (size_t)(m0 + srow) * K + skk;
    const f16* gA1 = gA0 + 16 * K;
    const f16* gB0 = Bm + (size_t)(n0 + srow) * K + skk;
    const f16* gB1 = gB0 + 16 * K;
    f16* lA0 = As + wave * 1024;   // 32 rows * 32 f16
    f16* lA1 = lA0 + 512;
    f16* lB0 = Bs + wave * 1024;
    f16* lB1 = lB0 + 512;

    // fragment read: A[m=lane&15][k=(lane>>4)*8 + j]
    const int fr = lane & 15;
    const int fk = (lane >> 4) * 8;
    const f16* rA = As + fr * 32 + fk;
    const f16* rB = Bs + fr * 32 + fk;

    for (int k0 = 0; k0 < K; k0 += 32) {
        GLL(gA0, lA0); GLL(gA1, lA1); GLL(gB0, lB0); GLL(gB1, lB1);
        gA0 += 32; gA1 += 32; gB0 += 32; gB1 += 32;
        __syncthreads();   // drains vmcnt (global_load_lds) + barrier

        f16x8 af[4], bf[4];
#pragma unroll
        for (int mt = 0; mt < 4; ++mt) af[mt] = *(const f16x8*)(rA + (wm + mt * 16) * 32);
#pragma unroll
        for (int nt = 0; nt < 4; ++nt) bf[nt] = *(const f16x8*)(rB + (wn + nt * 16) * 32);
#pragma unroll
        for (int mt = 0; mt < 4; ++mt)
#pragma unroll
            for (int nt = 0; nt < 4; ++nt)
                acc[mt][nt] = __builtin_amdgcn_mfma_f32_16x16x32_f16(af[mt], bf[nt],
                                                                     acc[mt][nt], 0, 0, 0);
        __syncthreads();
    }

    // epilogue: C/D layout col=lane&15, row=(lane>>4)*4+reg  (m89/m91-verified)
    const int crow = (lane >> 4) * 4;
    const int ccol = lane & 15;
#pragma unroll
    for (int nt = 0; nt < 4; ++nt) {
        const int n  = n0 + wn + nt * 16 + ccol;
        const float bn = bias[n];
#pragma unroll
        for (int mt = 0; mt < 4; ++mt) {
            const int m = m0 + wm + mt * 16 + crow;
            size_t base = (size_t)m * N + n;
#pragma unroll
            for (int r = 0; r < 4; ++r)
                C[base + (size_t)r * N] = acc[mt][nt][r] + bn;
        }
    }
}

// ---------------------------------------------------------------------------
// LSTM recurrence: one block per batch sample b (B=64 blocks, 512 threads).
// Thread j owns c[b,j]/h[b,j]; h lives in LDS as f16; W streamed from L2 (f16).
// Writes cell states Cb[(t*B+b)*H + j] (f16) for the output GEMM.
// ---------------------------------------------------------------------------
__global__ __launch_bounds__(512) void lstm_kernel(
    const float* __restrict__ h0, const float* __restrict__ c0,
    const float* __restrict__ Gx, const f16* __restrict__ Wr,
    f16* __restrict__ Cb)
{
    const int b = blockIdx.x;
    const int j = threadIdx.x;
    __shared__ f16 hs[H_SZ];

    float c = c0[b * H_SZ + j];
    hs[j] = (f16)h0[b * H_SZ + j];
    const f16* w0 = Wr + (size_t)j * 4 * H_SZ;  // 4 contiguous rows (i,f,g,o for this j)
    __syncthreads();

    for (int t = 0; t < T_STEPS; ++t) {
        const float* gx = Gx + (size_t)(t * B_SZ + b) * G4 + j;
        float a0 = gx[0];
        float a1 = gx[H_SZ];
        float a2 = gx[2 * H_SZ];
        float a3 = gx[3 * H_SZ];

        for (int k = 0; k < H_SZ; k += 32) {
            f16x8 hv0 = *(const f16x8*)(hs + k);
            f16x8 hv1 = *(const f16x8*)(hs + k + 8);
            f16x8 hv2 = *(const f16x8*)(hs + k + 16);
            f16x8 hv3 = *(const f16x8*)(hs + k + 24);
            const f16* wg = w0 + k;
            // gate 0 (i)
            a0 = dot8(*(const f16x8*)(wg), hv0, a0);
            a0 = dot8(*(const f16x8*)(wg + 8), hv1, a0);
            a0 = dot8(*(const f16x8*)(wg + 16), hv2, a0);
            a0 = dot8(*(const f16x8*)(wg + 24), hv3, a0);
            // gate 1 (f)
            a1 = dot8(*(const f16x8*)(wg + H_SZ), hv0, a1);
            a1 = dot8(*(const f16x8*)(wg + H_SZ + 8), hv1, a1);
            a1 = dot8(*(const f16x8*)(wg + H_SZ + 16), hv2, a1);
            a1 = dot8(*(const f16x8*)(wg + H_SZ + 24), hv3, a1);
            // gate 2 (g)
            a2 = dot8(*(const f16x8*)(wg + 2 * H_SZ), hv0, a2);
            a2 = dot8(*(const f16x8*)(wg + 2 * H_SZ + 8), hv1, a2);
            a2 = dot8(*(const f16x8*)(wg + 2 * H_SZ + 16), hv2, a2);
            a2 = dot8(*(const f16x8*)(wg + 2 * H_SZ + 24), hv3, a2);
            // gate 3 (o)
            a3 = dot8(*(const f16x8*)(wg + 3 * H_SZ), hv0, a3);
            a3 = dot8(*(const f16x8*)(wg + 3 * H_SZ + 8), hv1, a3);
            a3 = dot8(*(const f16x8*)(wg + 3 * H_SZ + 16), hv2, a3);
            a3 = dot8(*(const f16x8*)(wg + 3 * H_SZ + 24), hv3, a3);
        }

        float ig = sigmoidf_fast(a0);
        float fg = sigmoidf_fast(a1);
        float gg = tanhf_fast(a2);
        float og = sigmoidf_fast(a3);
        c = fg * c + ig * gg;
        float hn = og * tanhf_fast(c);

        Cb[(size_t)(t * B_SZ + b) * H_SZ + j] = (f16)c;

        __syncthreads();           // everyone done reading old h
        hs[j] = (f16)hn;
        __syncthreads();           // new h visible
    }
}

// ---------------------------------------------------------------------------
extern "C" void kernel_launch(void* const* d_in, const int* in_sizes, int n_in,
                              void* d_out, int out_size, void* d_ws, size_t ws_size,
                              hipStream_t stream)
{
    const float* h0    = (const float*)d_in[0];
    const float* c0    = (const float*)d_in[1];
    // d_in[2] = context: unused by the reference
    const int*   y     = (const int*)d_in[3];
    const float* embed = (const float*)d_in[4];
    const float* Wih   = (const float*)d_in[5];
    const float* bih   = (const float*)d_in[6];
    const float* Whh   = (const float*)d_in[7];
    const float* bhh   = (const float*)d_in[8];
    const float* Wout  = (const float*)d_in[9];
    const float* bout  = (const float*)d_in[10];
    float* out = (float*)d_out;

    char* ws = (char*)d_ws;
    f16*   Woutf = (f16*)ws;   ws += (size_t)V_SZ * H_SZ * 2;        // 32,768,000
    float* Gx    = (float*)ws; ws += (size_t)T_STEPS * B_SZ * G4 * 4;// 33,554,432
    f16*   Xf    = (f16*)ws;   ws += (size_t)T_STEPS * B_SZ * E_SZ * 2; // 2,097,152
    f16*   Wihf  = (f16*)ws;   ws += (size_t)G4 * E_SZ * 2;          // 1,048,576
    f16*   Wrf   = (f16*)ws;   ws += (size_t)G4 * H_SZ * 2;          // 2,097,152
    f16*   Cb    = (f16*)ws;   ws += (size_t)T_STEPS * B_SZ * H_SZ * 2; // 4,194,304
    float* bsum  = (float*)ws; ws += (size_t)G4 * 4;                 // 8,192

    prep_kernel<<<4096, 256, 0, stream>>>(Wih, Whh, Wout, bih, bhh, embed, y,
                                          Xf, Wihf, Wrf, Woutf, bsum);
    // Gx[tb][n] = X @ W_ih^T + (b_ih + b_hh)
    gemm_f16<E_SZ><<<dim3(G4 / 128, (T_STEPS * B_SZ) / 128), 256, 0, stream>>>(
        Xf, Wihf, bsum, Gx, G4);
    lstm_kernel<<<B_SZ, H_SZ, 0, stream>>>(h0, c0, Gx, Wrf, Cb);
    // out[tb][v] = C_cell @ W_out^T + b_out
    gemm_f16<H_SZ><<<dim3(V_SZ / 128, (T_STEPS * B_SZ) / 128), 256, 0, stream>>>(
        Cb, Woutf, bout, out, V_SZ);
}